// Round 4
// baseline (51.699 us; speedup 1.0000x reference)
//
#include <hip/hip_runtime.h>
#include <math.h>

// One 64-lane wave per token row; lane e holds logit for expert e (E=64).
// Top-2 via butterfly argmax (tie-break to smaller index, matching
// jax.lax.top_k); normalized weights = softmax over the top-2 logits
// (global softmax denominator cancels under normalization).
__global__ __launch_bounds__(256) void moe_router_kernel(
    const float* __restrict__ logits, float* __restrict__ out_idx,
    float* __restrict__ out_w, int N) {
    int gtid = blockIdx.x * blockDim.x + threadIdx.x;
    int row = gtid >> 6;
    int lane = threadIdx.x & 63;
    if (row >= N) return;

    float v = logits[row * 64 + lane];

    float bv = v; int bi = lane;
    #pragma unroll
    for (int off = 32; off >= 1; off >>= 1) {
        float ov = __shfl_xor(bv, off);
        int   oi = __shfl_xor(bi, off);
        if (ov > bv || (ov == bv && oi < bi)) { bv = ov; bi = oi; }
    }
    float sv = (lane == bi) ? -INFINITY : v;
    int si = lane;
    #pragma unroll
    for (int off = 32; off >= 1; off >>= 1) {
        float ov = __shfl_xor(sv, off);
        int   oi = __shfl_xor(si, off);
        if (ov > sv || (ov == sv && oi < si)) { sv = ov; si = oi; }
    }

    if (lane == 0) {
        float e  = expf(sv - bv);          // <= 1
        float w0 = 1.0f / (1.0f + e);
        out_idx[row * 2 + 0] = (float)bi;
        out_idx[row * 2 + 1] = (float)si;
        out_w[row * 2 + 0]   = w0;
        out_w[row * 2 + 1]   = e * w0;
    }
}

extern "C" void kernel_launch(void* const* d_in, const int* in_sizes, int n_in,
                              void* d_out, int out_size, void* d_ws, size_t ws_size,
                              hipStream_t stream) {
    const float* hidden = (const float*)d_in[0];   // [N, H] f32
    const float* router = (const float*)d_in[1];   // [N, E] f32 logits

    const int N = 8192, H = 4096;
    const long long combined_elems = (long long)N * H;   // 33,554,432

    float* out_combined = (float*)d_out;
    float* out_idx      = out_combined + combined_elems; // [N, 2] as f32
    float* out_w        = out_idx + (long long)N * 2;    // [N, 2] f32

    // Router first (tiny), then the bulk copy via the driver's tuned blit.
    int waves_per_block = 256 / 64;
    int blocks = (N + waves_per_block - 1) / waves_per_block;
    moe_router_kernel<<<blocks, 256, 0, stream>>>(router, out_idx, out_w, N);

    hipMemcpyAsync(out_combined, hidden, combined_elems * sizeof(float),
                   hipMemcpyDeviceToDevice, stream);
}